// Round 16
// baseline (75.458 us; speedup 1.0000x reference)
//
#include <hip/hip_runtime.h>
#include <hip/hip_bf16.h>

#define BQ 4
#define LQ 4096
#define DM 512
#define DK 64
#define NROWS (BQ * DK)        // 256
#define TOPK 16
#define CAND 32

typedef __attribute__((ext_vector_type(4))) float f32x4;
typedef __attribute__((ext_vector_type(8))) short short8v;
typedef __attribute__((ext_vector_type(16))) float f32x16;

__device__ __forceinline__ unsigned short f2bf(float x) {
  unsigned u = __builtin_bit_cast(unsigned, x);
  return (unsigned short)((u + 0x7FFFu + ((u >> 16) & 1u)) >> 16);
}
__device__ __forceinline__ float bf2f(unsigned short h) {
  unsigned u = ((unsigned)h) << 16;
  return __builtin_bit_cast(float, u);
}

// MFMA->VALU drain (epilogue): nothing crosses; 32 wait cycles.
__device__ __forceinline__ void mfma_drain() {
  __builtin_amdgcn_sched_barrier(0);
  asm volatile("s_nop 7\n\ts_nop 7\n\ts_nop 7\n\ts_nop 7" ::: "memory");
  __builtin_amdgcn_sched_barrier(0);
}

// counted wait on outstanding VMEM (rule #18: sched_barrier after waitcnt so
// the compiler cannot hoist register consumers above the wait).
#define VMCNT_(n) asm volatile("s_waitcnt vmcnt(" #n ")" ::: "memory")
#define VMCNT(n)                        \
  do {                                  \
    VMCNT_(n);                          \
    __builtin_amdgcn_sched_barrier(0);  \
  } while (0)

// ---------------------------------------------------------------------------
// Kernel 0 (r13-proven): W^T hi/lo bf16 in fragment-packed layout.
// wpack[((plane*2+nt)*32+ks)*512 + lane*8 + i]
// ---------------------------------------------------------------------------
__global__ __launch_bounds__(256) void wprep_kernel(
    const float* __restrict__ Wq, short* __restrict__ wpack) {
  const int ks = blockIdx.x;
  const int t = threadIdx.x;
  const int lane = t & 63, half = t >> 6;
  const int plane = half >> 1, nt = half & 1;
  const int r = nt * 32 + (lane & 31);
  const int kb = 16 * ks + 8 * (lane >> 5);
  short8v o;
#pragma unroll
  for (int i = 0; i < 8; ++i) {
    float v = Wq[(size_t)(kb + i) * DK + r];
    unsigned short h = f2bf(v);
    o[i] = plane ? (short)f2bf(v - bf2f(h)) : (short)h;
  }
  *(short8v*)(&wpack[(((size_t)plane * 2 + nt) * 32 + ks) * 512 + lane * 8]) = o;
}

// ---------------------------------------------------------------------------
// Kernel 1 v8: K-split split-bf16 MFMA projection with ASM-PIPELINED loads.
// All x/W global loads are volatile inline-asm global_load_dwordx4 into
// static ring buffers (xr[2] one kb ahead, wr3[3] two steps ahead), gated by
// hand-counted s_waitcnt vmcnt(N) — the compiler cannot sink the prefetches
// (r15 falsified the launch_bounds fix: allocator kept 80 VGPRs and
// serialized every load). vmcnt never drains to 0 mid-loop.
// r12-proven MFMA hazard fencing (fused asm, s_nop 4 / 7+3) unchanged.
// ---------------------------------------------------------------------------
#define XLOAD(buf, kb_)                                                        \
  do {                                                                         \
    const float* xbase_ = xb + (kb_) * 64;                                     \
    asm volatile("global_load_dwordx4 %0, %1, off" : "=v"(buf[0]) : "v"(xbase_));            \
    asm volatile("global_load_dwordx4 %0, %1, off offset:16" : "=v"(buf[1]) : "v"(xbase_));  \
    asm volatile("global_load_dwordx4 %0, %1, off offset:64" : "=v"(buf[2]) : "v"(xbase_));  \
    asm volatile("global_load_dwordx4 %0, %1, off offset:80" : "=v"(buf[3]) : "v"(xbase_));  \
    asm volatile("global_load_dwordx4 %0, %1, off offset:128" : "=v"(buf[4]) : "v"(xbase_)); \
    asm volatile("global_load_dwordx4 %0, %1, off offset:144" : "=v"(buf[5]) : "v"(xbase_)); \
    asm volatile("global_load_dwordx4 %0, %1, off offset:192" : "=v"(buf[6]) : "v"(xbase_)); \
    asm volatile("global_load_dwordx4 %0, %1, off offset:208" : "=v"(buf[7]) : "v"(xbase_)); \
  } while (0)

#define WLOADR(buf, ksl_)                                                      \
  do {                                                                         \
    const short* wb_ = wp0 + ((size_t)(kh * 16 + (ksl_)) << 9);                \
    asm volatile("global_load_dwordx4 %0, %1, off" : "=v"(buf[0]) : "v"(wb_)); \
    asm volatile("global_load_dwordx4 %0, %1, off" : "=v"(buf[1]) : "v"(wb_ + (64 << 9))); \
    asm volatile("global_load_dwordx4 %0, %1, off" : "=v"(buf[2]) : "v"(wb_ + (32 << 9))); \
    asm volatile("global_load_dwordx4 %0, %1, off" : "=v"(buf[3]) : "v"(wb_ + (96 << 9))); \
  } while (0)

#define STEP(kb_, s_, vm_)                                                     \
  do {                                                                         \
    if ((s_) == 0 && (kb_) < 3) XLOAD(xr[((kb_) + 1) & 1], (kb_) + 1);         \
    if (4 * (kb_) + (s_) < 14) WLOADR(wr3[(4 * (kb_) + (s_) + 2) % 3],         \
                                      4 * (kb_) + (s_) + 2);                   \
    VMCNT(vm_);                                                                \
    const f32x4* xa_ = xr[(kb_) & 1] + 2 * (s_);                               \
    float f_[8] = {xa_[0][0], xa_[0][1], xa_[0][2], xa_[0][3],                 \
                   xa_[1][0], xa_[1][1], xa_[1][2], xa_[1][3]};                \
    short8v ah_, al_;                                                          \
    _Pragma("unroll")                                                          \
    for (int i_ = 0; i_ < 8; ++i_) {                                           \
      unsigned short h_ = f2bf(f_[i_]);                                        \
      ah_[i_] = (short)h_;                                                     \
      al_[i_] = (short)f2bf(f_[i_] - bf2f(h_));                                \
    }                                                                          \
    short8v* w_ = wr3[(4 * (kb_) + (s_)) % 3];                                 \
    asm volatile(                                                              \
        "s_nop 4\n\t"                                                          \
        "v_mfma_f32_32x32x16_bf16 %0, %2, %4, %0\n\t"                          \
        "v_mfma_f32_32x32x16_bf16 %0, %2, %5, %0\n\t"                          \
        "v_mfma_f32_32x32x16_bf16 %0, %3, %4, %0\n\t"                          \
        "v_mfma_f32_32x32x16_bf16 %1, %2, %6, %1\n\t"                          \
        "v_mfma_f32_32x32x16_bf16 %1, %2, %7, %1\n\t"                          \
        "v_mfma_f32_32x32x16_bf16 %1, %3, %6, %1\n\t"                          \
        "s_nop 7\n\t"                                                          \
        "s_nop 3"                                                              \
        : "+v"(acc[0]), "+v"(acc[1])                                           \
        : "v"(ah_), "v"(al_), "v"(w_[0]), "v"(w_[1]), "v"(w_[2]), "v"(w_[3])); \
  } while (0)

__global__ __launch_bounds__(256, 2) void proj_kernel(
    const float* __restrict__ q_in, const float* __restrict__ k_in,
    const float* __restrict__ v_in, const short* __restrict__ wpack,
    const float* __restrict__ bq, float* __restrict__ ws) {
  const float* x = blockIdx.z == 0 ? q_in : (blockIdx.z == 1 ? k_in : v_in);
  float* outp = ws + (size_t)blockIdx.z * (size_t)(NROWS * LQ);

  __shared__ __align__(16) float smem[4352];   // red[4096] / ts[4352] overlay

  const int tid = threadIdx.x;
  const int l = tid & 63, wv = tid >> 6;
  const int tile = wv >> 1, kh = wv & 1;
  const int R0 = blockIdx.x * 64 + tile * 32;
  const int koff = 8 * (l >> 5);

  const float* xb = x + (size_t)(R0 + (l & 31)) * DM + kh * 256 + koff;
  const short* wp0 = wpack + l * 8;            // lane base

  f32x16 acc[2];
#pragma unroll
  for (int nt = 0; nt < 2; ++nt)
#pragma unroll
    for (int i = 0; i < 16; ++i) acc[nt][i] = 0.f;

  f32x4 xr[2][8];
  short8v wr3[3][4];

  // prologue: X0 + W0,W1 in flight (16 outstanding)
  XLOAD(xr[0], 0);
  WLOADR(wr3[0], 0);
  WLOADR(wr3[1], 1);

  // 16 steps; vmcnt derived from the issue schedule (see r16 theory).
  STEP(0, 0, 16); STEP(0, 1, 16); STEP(0, 2, 8);  STEP(0, 3, 8);
  STEP(1, 0, 16); STEP(1, 1, 16); STEP(1, 2, 8);  STEP(1, 3, 8);
  STEP(2, 0, 16); STEP(2, 1, 16); STEP(2, 2, 8);  STEP(2, 3, 8);
  STEP(3, 0, 8);  STEP(3, 1, 8);  STEP(3, 2, 4);  STEP(3, 3, 0);

  // ---- merge K-halves via LDS (kh=1 writes, kh=0 adds) ----
  mfma_drain();
  if (kh == 1) {
#pragma unroll
    for (int nt = 0; nt < 2; ++nt)
#pragma unroll
      for (int r = 0; r < 16; ++r)
        smem[tile * 2048 + nt * 1024 + r * 64 + l] = acc[nt][r];
  }
  __syncthreads();
  if (kh == 0) {
#pragma unroll
    for (int nt = 0; nt < 2; ++nt)
#pragma unroll
      for (int r = 0; r < 16; ++r)
        acc[nt][r] += smem[tile * 2048 + nt * 1024 + r * 64 + l];
  }
  __syncthreads();   // red region dead; ts overlay safe

  // ---- epilogue (kh=0 waves): bias + per-wave LDS transpose + stores ----
  if (kh == 0) {
    const int b = R0 >> 12, i0 = R0 & (LQ - 1);
    float bb[2] = {bq[l & 31], bq[32 + (l & 31)]};
#pragma unroll
    for (int nt = 0; nt < 2; ++nt) {
      float* area = smem + (tile * 2 + nt) * 1088;
#pragma unroll
      for (int r = 0; r < 16; ++r) {
        int io = (r & 3) + 8 * (r >> 2) + 4 * (l >> 5);
        area[(l & 31) * 34 + io] = acc[nt][r] + bb[nt];
      }
      const int e = l & 15, jg = l >> 4;
#pragma unroll
      for (int p = 0; p < 8; ++p) {
        int jj = jg * 8 + p;
        float2 v = *reinterpret_cast<const float2*>(area + jj * 34 + e * 2);
        *reinterpret_cast<float2*>(
            &outp[((size_t)b * DK + nt * 32 + jj) * LQ + i0 + e * 2]) = v;
      }
    }
  }
}

// ---------------------------------------------------------------------------
// Kernel 2 (r15-proven): fused corr+topk, 8 waves, scratch-free screen.
// ---------------------------------------------------------------------------
__global__ __launch_bounds__(512) void corr_topk_kernel(
    const float* __restrict__ qp, const float* __restrict__ kp,
    float* __restrict__ lw) {
  const int row = blockIdx.x;
  const int tid = threadIdx.x;
  __shared__ __align__(16) short qs[3 * 4112 + 4096];  // 32864 B; red overlay
  __shared__ __align__(16) short ks[4096];             // 8192 B
  __shared__ __align__(16) float qf[LQ];               // fp32 for refine
  __shared__ __align__(16) float kf[LQ];
  __shared__ unsigned wk[128];
  __shared__ unsigned scand[CAND];
  __shared__ float rS[CAND];
  __shared__ float ordv[TOPK]; __shared__ int ordl[TOPK];

  const float* qr = qp + ((size_t)row << 12);
  const float* kr = kp + ((size_t)row << 12);

  {
    const float4* q4 = (const float4*)qr;
    float4 v0 = q4[tid * 2], v1 = q4[tid * 2 + 1];
    float4 v2 = q4[(tid * 2 + 2) & 1023];
    ((float4*)qf)[tid * 2] = v0;
    ((float4*)qf)[tid * 2 + 1] = v1;
    float f[12] = {v0.x, v0.y, v0.z, v0.w, v1.x, v1.y, v1.z, v1.w,
                   v2.x, v2.y, v2.z, v2.w};
#pragma unroll
    for (int r = 0; r < 4; ++r) {
      short8v o;
#pragma unroll
      for (int i = 0; i < 8; ++i) o[i] = (short)f2bf(f[i + r]);
      *(short8v*)(&qs[r * 4112 + tid * 8]) = o;
    }
    const float4* k4 = (const float4*)kr;
    float4 w0 = k4[tid * 2], w1 = k4[tid * 2 + 1];
    ((float4*)kf)[tid * 2] = w0;
    ((float4*)kf)[tid * 2 + 1] = w1;
    float g[8] = {w0.x, w0.y, w0.z, w0.w, w1.x, w1.y, w1.z, w1.w};
    int Q = tid;
    int Qs = Q ^ ((Q >> 3) & 7);
    short8v o;
#pragma unroll
    for (int i = 0; i < 8; ++i) o[i] = (short)f2bf(g[i]);
    *(short8v*)(&ks[Qs << 3]) = o;
  }
  __syncthreads();

  const int l = tid & 63, wv = tid >> 6;    // 8 waves
  const int Oq = ((8 * (l >> 5) - 32 * (l & 31)) & 4095) >> 3;
  const int rB = (l & 31) & 3;
  const int Ce = (l & 31) + 8 * (l >> 5) - rB;
  const short* qb = qs + rB * 4112;

  f32x16 acc[4];
#pragma unroll
  for (int M = 0; M < 4; ++M)
#pragma unroll
    for (int i = 0; i < 16; ++i) acc[M][i] = 0.f;

  const int J0 = wv * 32;
#pragma unroll 2
  for (int jb = 0; jb < 32; ++jb) {
    const int J = J0 + jb;
    int e1 = (Ce + 16 * J) & 4095;
    int e2 = (e1 + 4) & 4095;
    uint2 blo = *(const uint2*)(qb + e1);
    uint2 bhi = *(const uint2*)(qb + e2);
    int4 bi; bi.x = blo.x; bi.y = blo.y; bi.z = bhi.x; bi.w = bhi.y;
    short8v bf = __builtin_bit_cast(short8v, bi);
    const int Dq = 2 * J;
#pragma unroll
    for (int M = 0; M < 4; ++M) {
      int Q = (Oq + Dq - 128 * M) & 511;
      Q ^= (Q >> 3) & 7;
      short8v af = *(const short8v*)(&ks[Q << 3]);
      asm volatile("v_mfma_f32_32x32x16_bf16 %0, %1, %2, %0"
                   : "+v"(acc[M]) : "v"(af), "v"(bf));
    }
  }

  mfma_drain();
  __syncthreads();
  float* red = (float*)qs;               // 2 strips x 4096 f32
  const int strip = (wv & 1) * 4096;
  const int ch4 = (l >> 5) * 4, cn = l & 31;
#define RIDX(M, r) (strip + ((M) << 10) + 32 * (((r)&3) + 8 * ((r) >> 2) + ch4) + cn)
  if (wv < 2) {
#pragma unroll
    for (int M = 0; M < 4; ++M)
#pragma unroll
      for (int r = 0; r < 16; ++r) red[RIDX(M, r)] = acc[M][r];
  }
  __syncthreads();
  if (wv >= 2 && wv < 4) {
#pragma unroll
    for (int M = 0; M < 4; ++M)
#pragma unroll
      for (int r = 0; r < 16; ++r) red[RIDX(M, r)] += acc[M][r];
  }
  __syncthreads();
  if (wv >= 4 && wv < 6) {
#pragma unroll
    for (int M = 0; M < 4; ++M)
#pragma unroll
      for (int r = 0; r < 16; ++r) red[RIDX(M, r)] += acc[M][r];
  }
  __syncthreads();
  if (wv >= 6) {
#pragma unroll
    for (int M = 0; M < 4; ++M)
#pragma unroll
      for (int r = 0; r < 16; ++r) red[RIDX(M, r)] += acc[M][r];
  }
  __syncthreads();
#undef RIDX

  {
    unsigned key[8];
#pragma unroll
    for (int i = 0; i < 8; ++i) {
      int tau = wv * 512 + i * 64 + l;
      float v = red[tau] + red[4096 + tau];
      unsigned u = __builtin_bit_cast(unsigned, fabsf(v));
      key[i] = (u & 0xFFFFF000u) | (unsigned)(4095 - tau);
    }
    unsigned bkey = key[0];
#pragma unroll
    for (int i = 1; i < 8; ++i) bkey = key[i] > bkey ? key[i] : bkey;
    for (int round = 0; round < 16; ++round) {
      unsigned m = bkey;
#pragma unroll
      for (int off = 1; off < 64; off <<= 1) {
        unsigned o = __shfl_xor(m, off);
        m = o > m ? o : m;
      }
      if (l == 0) wk[wv * 16 + round] = m;
#pragma unroll
      for (int i = 0; i < 8; ++i) key[i] = (key[i] == m) ? 0u : key[i];
      bkey = key[0];
#pragma unroll
      for (int i = 1; i < 8; ++i) bkey = key[i] > bkey ? key[i] : bkey;
    }
  }
  __syncthreads();

  if (tid < 128) {
    unsigned ki = wk[tid];
    int rank = 0;
    for (int j = 0; j < 128; ++j) rank += (wk[j] > ki);
    if (rank < CAND) scand[rank] = ki;
  }
  __syncthreads();

  {
    const int ci = tid >> 4, sub = tid & 15;
    const int lag = 4095 - (int)(scand[ci] & 0xFFFu);
    float S0 = 0.f, S1 = 0.f, S2 = 0.f, S3 = 0.f;
    for (int it = 0; it < 256; it += 4) {
      int t0 = (it + 0) * 16 + sub, t1 = (it + 1) * 16 + sub;
      int t2 = (it + 2) * 16 + sub, t3 = (it + 3) * 16 + sub;
      S0 = fmaf(kf[t0], qf[(t0 + lag) & 4095], S0);
      S1 = fmaf(kf[t1], qf[(t1 + lag) & 4095], S1);
      S2 = fmaf(kf[t2], qf[(t2 + lag) & 4095], S2);
      S3 = fmaf(kf[t3], qf[(t3 + lag) & 4095], S3);
    }
    float S = (S0 + S1) + (S2 + S3);
    S += __shfl_xor(S, 1);
    S += __shfl_xor(S, 2);
    S += __shfl_xor(S, 4);
    S += __shfl_xor(S, 8);
    if (sub == 0) rS[ci] = S;
  }
  __syncthreads();

  if (tid < CAND) {
    float vi = fabsf(rS[tid]);
    int ii = 4095 - (int)(scand[tid] & 0xFFFu);
    int rank = 0;
    for (int j = 0; j < CAND; ++j) {
      float vj = fabsf(rS[j]);
      int ij = 4095 - (int)(scand[j] & 0xFFFu);
      rank += (vj > vi) || (vj == vi && ij < ii);
    }
    if (rank < TOPK) { ordv[rank] = vi; ordl[rank] = ii; }
  }
  __syncthreads();

  if (tid == 0) {
    float m0 = ordv[0], s = 0.f, e[TOPK];
    for (int k = 0; k < TOPK; ++k) { e[k] = expf(ordv[k] - m0); s += e[k]; }
    float inv = 1.f / s;
    int* ip = (int*)(lw + (size_t)row * 32);
    for (int k = 0; k < TOPK; ++k) {
      ip[k] = ordl[k];
      ((float*)ip)[TOPK + k] = e[k] * inv;
    }
  }
}

// ---------------------------------------------------------------------------
// Kernel 4: aggregation  aggT[row][t] = sum_k w_k * v[row][(t+lag_k)%L]
// ---------------------------------------------------------------------------
__global__ void agg_kernel(const float* __restrict__ vpT,
                           const float* __restrict__ lw,
                           float* __restrict__ aggT) {
  const int row = blockIdx.x, tid = threadIdx.x;
  __shared__ __align__(16) float vr[2 * LQ];
  __shared__ float w[TOPK]; __shared__ int lg[TOPK];

  const float* v0 = vpT + (size_t)row * LQ;
  for (int x = tid; x < LQ; x += 256) {
    float val = v0[x];
    vr[x] = val; vr[x + LQ] = val;
  }
  if (tid < TOPK) {
    lg[tid] = ((const int*)(lw + (size_t)row * 32))[tid];
    w[tid] = lw[(size_t)row * 32 + TOPK + tid];
  }
  __syncthreads();

  float wr[TOPK]; int lr[TOPK];
#pragma unroll
  for (int k = 0; k < TOPK; ++k) { wr[k] = w[k]; lr[k] = lg[k]; }

  for (int m = 0; m < 16; ++m) {
    int t = m * 256 + tid;
    float a = 0.f;
#pragma unroll
    for (int k = 0; k < TOPK; ++k) a = fmaf(wr[k], vr[t + lr[k]], a);
    aggT[(size_t)row * LQ + t] = a;
  }
}

// ---------------------------------------------------------------------------
// Kernel 5: transpose + head-broadcast  out[b][t][c] = aggT[b][c&63][t]
// ---------------------------------------------------------------------------
__global__ void trans_kernel(const float* __restrict__ aggT,
                             float* __restrict__ out) {
  const int b = blockIdx.y;
  const int t0 = blockIdx.x * 64;
  const int tid = threadIdx.x;
  __shared__ float ts[64][65];

#pragma unroll
  for (int v = 0; v < 16; ++v) {
    int f = v * 256 + tid;
    int d = f >> 6, tt = f & 63;
    ts[d][tt] = aggT[((size_t)b * DK + d) * LQ + t0 + tt];
  }
  __syncthreads();

#pragma unroll
  for (int v = 0; v < 128; ++v) {
    int f = v * 256 + tid;
    int tt = f >> 9, c = f & 511;
    out[((size_t)b * LQ + t0 + tt) * (8 * DK) + c] = ts[c & 63][tt];
  }
}

// ---------------------------------------------------------------------------
// ws layout (floats): [0,1M) qp  [1M,2M) kp  [2M,3M) vp
//   [3M,+8K) lw  [4M,5M) aggT  [5M,+32K floats) wpack (128KB)
// ---------------------------------------------------------------------------
extern "C" void kernel_launch(void* const* d_in, const int* in_sizes, int n_in,
                              void* d_out, int out_size, void* d_ws, size_t ws_size,
                              hipStream_t stream) {
  const float* q_in = (const float*)d_in[0];
  const float* k_in = (const float*)d_in[1];
  const float* v_in = (const float*)d_in[2];
  const float* Wq   = (const float*)d_in[3];
  const float* bq   = (const float*)d_in[4];
  float* out = (float*)d_out;
  float* ws  = (float*)d_ws;

  const size_t M = (size_t)NROWS * LQ;        // 1,048,576 floats
  float* qp    = ws;
  float* kp    = ws + M;
  float* vp    = ws + 2 * M;
  float* lw    = ws + 3 * M;
  float* aggT  = ws + 4 * M;
  short* wpack = (short*)(ws + 5 * M);

  wprep_kernel<<<32, 256, 0, stream>>>(Wq, wpack);
  proj_kernel<<<dim3(256, 1, 3), 256, 0, stream>>>(q_in, k_in, v_in, wpack,
                                                   bq, ws);
  corr_topk_kernel<<<NROWS, 512, 0, stream>>>(qp, kp, lw);
  agg_kernel<<<NROWS, 256, 0, stream>>>(vp, lw, aggT);
  trans_kernel<<<dim3(LQ / 64, BQ), 256, 0, stream>>>(aggT, out);
}